// Round 9
// baseline (669.012 us; speedup 1.0000x reference)
//
#include <hip/hip_runtime.h>

#define SEQ   2048
#define BATCH 4096
#define HID   6
#define BLK   256   // 4 waves/block; 8 elements/block (32 lanes each)

typedef float v2f __attribute__((ext_vector_type(2)));
typedef unsigned u2 __attribute__((ext_vector_type(2)));

// ---- fast HW math ----
__device__ __forceinline__ float fexp2(float a) {
#if __has_builtin(__builtin_amdgcn_exp2f)
  return __builtin_amdgcn_exp2f(a);
#else
  float r; asm("v_exp_f32 %0, %1" : "=v"(r) : "v"(a)); return r;
#endif
}
__device__ __forceinline__ float frcp(float a) {
#if __has_builtin(__builtin_amdgcn_rcpf)
  return __builtin_amdgcn_rcpf(a);
#else
  float r; asm("v_rcp_f32 %0, %1" : "=v"(r) : "v"(a)); return r;
#endif
}

// ---- DPP (VALU pipe): row_ror:8 = p-partner exchange within 16-row (R5-validated)
template <int CTRL>
__device__ __forceinline__ float dppf(float v) {
  int r = __builtin_amdgcn_update_dpp(0, __builtin_bit_cast(int, v), CTRL, 0xF, 0xF, true);
  return __builtin_bit_cast(float, r);
}

// ---- ds_swizzle broadcast of lane (group-base + J) to the 8-group (R7-validated)
// BitMode offset = (xor<<10)|(or<<5)|and ; and=0x18 keeps (p,layer) group bits.
template <int OFF>
__device__ __forceinline__ float swzf(float v) {
  int r = __builtin_amdgcn_ds_swizzle(__builtin_bit_cast(int, v), OFF);
  return __builtin_bit_cast(float, r);
}
#define BC0 0x18
#define BC1 0x38
#define BC2 0x58
#define BC3 0x78
#define BC4 0x98
#define BC5 0xB8

// lane l <-> l^16 exchange via v_permlane16_swap_b32 (R6-validated polarity:
// lanes with bit4 set take r.x, others r.y).
__device__ __forceinline__ float xor16f(float v, bool hi) {
#if __has_builtin(__builtin_amdgcn_permlane16_swap)
  u2 r = __builtin_amdgcn_permlane16_swap(__builtin_bit_cast(unsigned, v),
                                          __builtin_bit_cast(unsigned, v), false, false);
  return __builtin_bit_cast(float, hi ? r.x : r.y);
#else
  unsigned d = __builtin_bit_cast(unsigned, v), s = d;
  asm volatile("v_permlane16_swap_b32 %0, %1" : "+v"(d), "+v"(s));
  return __builtin_bit_cast(float, hi ? d : s);
#endif
}

// launch_bounds(256, 2): min 2 waves/EU caps VGPR at 128 -> guarantees the
// 2-waves/SIMD co-residency this layout exists for.
__global__ __launch_bounds__(BLK, 2) void lstm2_kernel(
    const float* __restrict__ x,
    const float* __restrict__ Wih0, const float* __restrict__ Whh0,
    const float* __restrict__ bih0, const float* __restrict__ bhh0,
    const float* __restrict__ Wih1, const float* __restrict__ Whh1,
    const float* __restrict__ bih1, const float* __restrict__ bhh1,
    const float* __restrict__ W2,   const float* __restrict__ b2,
    float* __restrict__ out)
{
  __shared__ float obuf[64][8];   // output rows staged; bulk-flushed every 64 steps

  const int tid = threadIdx.x;
  const int wib = tid >> 6;              // wave in block 0..3
  const int l6  = tid & 63;
  const int el  = l6 >> 5;               // element within wave 0..1
  const int r5  = l6 & 31;               // lane within element
  const bool hiL = (r5 & 16) != 0;       // layer-1 lanes (bit4, both elements)
  const int p   = (r5 >> 3) & 1;         // 0 -> rows {i,f}; 1 -> rows {g,o}
  const int u   = r5 & 7;                // unit 0..7 (6,7 pads)
  const int uu  = (u < HID) ? u : (HID - 1);
  const int b   = blockIdx.x * 8 + wib * 2 + el;   // batch element

  const int r0 = p ? (2 * HID + uu) : uu;           // i-row or g-row
  const int r1 = p ? (3 * HID + uu) : (HID + uu);   // f-row or o-row
  // activations: row0 = sigmoid (p0) / tanh (p1) via A*sigmoid(A*a)+Bc; row1 sigmoid.
  const float A  = p ? 2.f : 1.f;
  const float Bc = p ? -1.f : 0.f;
  const float K0 = p ? -2.8853900817779268f : -1.4426950408889634f;
  const float K1 = -1.4426950408889634f;
  const float KT =  2.8853900817779268f;   // tanh(c) = 1 - 2*rcp(1+exp2(KT*c))

  // K-folded weights, ABSOLUTE pair order k: {W[row][2k], W[row][2k+1]} (H=6 -> 3 pairs)
  v2f WA0[3], WA1[3], WB0[3], WB1[3];
  float BS0, BS1;
  if (!hiL) {
    WA0[0] = v2f{K0 * Wih0[r0 * 2 + 0], K0 * Wih0[r0 * 2 + 1]};
    WA1[0] = v2f{K1 * Wih0[r1 * 2 + 0], K1 * Wih0[r1 * 2 + 1]};
    WA0[1] = v2f{0.f, 0.f}; WA0[2] = v2f{0.f, 0.f};
    WA1[1] = v2f{0.f, 0.f}; WA1[2] = v2f{0.f, 0.f};
#pragma unroll
    for (int k = 0; k < 3; ++k) {
      WB0[k] = v2f{K0 * Whh0[r0 * HID + 2 * k], K0 * Whh0[r0 * HID + 2 * k + 1]};
      WB1[k] = v2f{K1 * Whh0[r1 * HID + 2 * k], K1 * Whh0[r1 * HID + 2 * k + 1]};
    }
    BS0 = K0 * (bih0[r0] + bhh0[r0]);
    BS1 = K1 * (bih0[r1] + bhh0[r1]);
  } else {
#pragma unroll
    for (int k = 0; k < 3; ++k) {
      WA0[k] = v2f{K0 * Wih1[r0 * HID + 2 * k], K0 * Wih1[r0 * HID + 2 * k + 1]};
      WA1[k] = v2f{K1 * Wih1[r1 * HID + 2 * k], K1 * Wih1[r1 * HID + 2 * k + 1]};
      WB0[k] = v2f{K0 * Whh1[r0 * HID + 2 * k], K0 * Whh1[r0 * HID + 2 * k + 1]};
      WB1[k] = v2f{K1 * Whh1[r1 * HID + 2 * k], K1 * Whh1[r1 * HID + 2 * k + 1]};
    }
    BS0 = K0 * (bih1[r0] + bhh1[r0]);
    BS1 = K1 * (bih1[r1] + bhh1[r1]);
  }
  const v2f w2p0 = v2f{W2[0], W2[1]}, w2p1 = v2f{W2[2], W2[3]}, w2p2 = v2f{W2[4], W2[5]};
  const float bout = b2[0];

  float h = 0.f, c = 0.f;   // own-layer state (replicated across p-halves)

  // absolute-order gather of own-group h (units 0..5 real) into 3 pairs
  auto gath = [&](float hv, v2f (&g)[3]) {
    g[0] = v2f{swzf<BC0>(hv), swzf<BC1>(hv)};
    g[1] = v2f{swzf<BC2>(hv), swzf<BC3>(hv)};
    g[2] = v2f{swzf<BC4>(hv), swzf<BC5>(hv)};
  };

  // one fused step: L0 lanes advance layer-0 (x, h0-rec), L1 lanes advance
  // layer-1 (h0 via permlane16, h1-rec). ov = out-dot of L1 lanes' g2.
  auto step = [&](v2f xc, float& ov) {
    v2f g2[3]; gath(h, g2);              // own-layer recurrence input
    float hs = xor16f(h, hiL);           // L1 lanes: partner h0[t-1]
    v2f g1[3]; gath(hs, g1);             // cross gather (L0: finite garbage, weight-0)
    v2f v10 = hiL ? g1[0] : xc;

    v2f a0v = __builtin_elementwise_fma(WA0[0], v10, v2f{BS0, 0.f});
    a0v = __builtin_elementwise_fma(WA0[1], g1[1], a0v);
    a0v = __builtin_elementwise_fma(WA0[2], g1[2], a0v);
    a0v = __builtin_elementwise_fma(WB0[0], g2[0], a0v);
    a0v = __builtin_elementwise_fma(WB0[1], g2[1], a0v);
    a0v = __builtin_elementwise_fma(WB0[2], g2[2], a0v);
    float a0 = a0v.x + a0v.y;

    v2f a1v = __builtin_elementwise_fma(WA1[0], v10, v2f{BS1, 0.f});
    a1v = __builtin_elementwise_fma(WA1[1], g1[1], a1v);
    a1v = __builtin_elementwise_fma(WA1[2], g1[2], a1v);
    a1v = __builtin_elementwise_fma(WB1[0], g2[0], a1v);
    a1v = __builtin_elementwise_fma(WB1[1], g2[1], a1v);
    a1v = __builtin_elementwise_fma(WB1[2], g2[2], a1v);
    float a1 = a1v.x + a1v.y;

    v2f ao = __builtin_elementwise_fma(w2p0, g2[0],
             __builtin_elementwise_fma(w2p1, g2[1],
             __builtin_elementwise_fma(w2p2, g2[2], v2f{bout, 0.f})));
    ov = ao.x + ao.y;

    // gates (R5-validated p-split): g0 = i|g, g1v = f|o; exchange across p (ror:8)
    float g0  = fmaf(A, frcp(1.f + fexp2(a0)), Bc);
    float g1v = frcp(1.f + fexp2(a1));
    float xg0 = dppf<0x128>(g0);
    float xg1 = dppf<0x128>(g1v);
    float m = g0 * xg0;                       // i*g (commutative across halves)
    float f = p ? xg1 : g1v;
    float o = p ? g1v : xg1;
    c = fmaf(f, c, m);
    float th = fmaf(-2.f, frcp(1.f + fexp2(c * KT)), 1.f);
    h = o * th;
  };

  // bulk flush: 64 rows x 8 elements, float2 per thread
  auto flush = [&](int rbase) {
    const int r = tid >> 2, jj = (tid & 3) * 2;
    float2 vv = *(const float2*)&obuf[r][jj];
    *(float2*)&out[(size_t)(rbase + r) * BATCH + blockIdx.x * 8 + jj] = vv;
  };

  const v2f* x2 = (const v2f*)x;
  // x prefetch queue, depth 4; invariant at loop-entry t: (xc..xn3) = x[t..t+3]
  v2f xc  = x2[(size_t)0 * BATCH + b];
  v2f xn1 = x2[(size_t)1 * BATCH + b];
  v2f xn2 = x2[(size_t)2 * BATCH + b];
  v2f xn3 = x2[(size_t)3 * BATCH + b];

  // t = 0 peel: L0 lanes compute h0[0]; L1 lanes' result is garbage -> reset
  {
    float ov;
    step(xc, ov);
    if (hiL) { h = 0.f; c = 0.f; }
    v2f xf = x2[(size_t)4 * BATCH + b];
    xc = xn1; xn1 = xn2; xn2 = xn3; xn3 = xf;
  }

  // iteration t: L0 -> h0[t]; L1 -> h1[t-1]; out row t-2 from L1's g2 gather
#pragma unroll 1
  for (int t = 1; t < SEQ; ++t) {
    int tf = t + 4; tf = (tf < SEQ) ? tf : (SEQ - 1);
    v2f xf = x2[(size_t)tf * BATCH + b];

    float ov;
    step(xc, ov);

    if (t >= 2) {
      const int r = t - 2;
      if (hiL && p == 0 && u == 0) obuf[r & 63][wib * 2 + el] = ov;  // lanes 16,48
      if ((r & 63) == 63) {          // uniform branch
        __syncthreads();
        flush(r - 63);
        __syncthreads();
      }
    }
    xc = xn1; xn1 = xn2; xn2 = xn3; xn3 = xf;
  }

  // epilogue: one more fused step -> h1[S-1] + out row S-2; final gather -> row S-1
  {
    float ov;
    step(xc, ov);
    if (hiL && p == 0 && u == 0) obuf[62][wib * 2 + el] = ov;
    v2f g2[3]; gath(h, g2);
    v2f ao = __builtin_elementwise_fma(w2p0, g2[0],
             __builtin_elementwise_fma(w2p1, g2[1],
             __builtin_elementwise_fma(w2p2, g2[2], v2f{bout, 0.f})));
    if (hiL && p == 0 && u == 0) obuf[63][wib * 2 + el] = ao.x + ao.y;
    __syncthreads();
    flush(SEQ - 64);
  }
}

extern "C" void kernel_launch(void* const* d_in, const int* in_sizes, int n_in,
                              void* d_out, int out_size, void* d_ws, size_t ws_size,
                              hipStream_t stream) {
  const float* x    = (const float*)d_in[0];
  const float* Wih0 = (const float*)d_in[1];
  const float* Whh0 = (const float*)d_in[2];
  const float* bih0 = (const float*)d_in[3];
  const float* bhh0 = (const float*)d_in[4];
  const float* Wih1 = (const float*)d_in[5];
  const float* Whh1 = (const float*)d_in[6];
  const float* bih1 = (const float*)d_in[7];
  const float* bhh1 = (const float*)d_in[8];
  const float* W2   = (const float*)d_in[9];
  const float* b2   = (const float*)d_in[10];
  float* out = (float*)d_out;

  dim3 grid(BATCH / 8);   // 512 blocks x 4 waves = 2048 waves = 2 waves/SIMD
  dim3 block(BLK);
  hipLaunchKernelGGL(lstm2_kernel, grid, block, 0, stream,
                     x, Wih0, Whh0, bih0, bhh0, Wih1, Whh1, bih1, bhh1, W2, b2, out);
}

// Round 10
// 660.905 us; speedup vs baseline: 1.0123x; 1.0123x over previous
//
#include <hip/hip_runtime.h>

#define SEQ   2048
#define BATCH 4096
#define HID   6
#define BLK   256   // 4 waves/block; 16 elements/block; 256 blocks -> 1 block/CU

typedef float v2f __attribute__((ext_vector_type(2)));
typedef unsigned u2 __attribute__((ext_vector_type(2)));

// ---- fast HW math ----
__device__ __forceinline__ float fexp2(float a) {
#if __has_builtin(__builtin_amdgcn_exp2f)
  return __builtin_amdgcn_exp2f(a);
#else
  float r; asm("v_exp_f32 %0, %1" : "=v"(r) : "v"(a)); return r;
#endif
}
__device__ __forceinline__ float frcp(float a) {
#if __has_builtin(__builtin_amdgcn_rcpf)
  return __builtin_amdgcn_rcpf(a);
#else
  float r; asm("v_rcp_f32 %0, %1" : "=v"(r) : "v"(a)); return r;
#endif
}

// ---- ds_swizzle broadcast of lane (8-group base + J) to the 8-group (R7-validated)
// BitMode offset = (xor<<10)|(or<<5)|and ; and=0x18 keeps element bits [4:3].
template <int OFF>
__device__ __forceinline__ float swzf(float v) {
  int r = __builtin_amdgcn_ds_swizzle(__builtin_bit_cast(int, v), OFF);
  return __builtin_bit_cast(float, r);
}
#define BC0 0x18
#define BC1 0x38
#define BC2 0x58
#define BC3 0x78
#define BC4 0x98
#define BC5 0xB8

// lane l <-> l^32 exchange via v_permlane32_swap_b32 (polarity validated R7 PASS:
// lanes >=32 take r.x, lanes <32 take r.y).
__device__ __forceinline__ float xhalf(float v, bool hi) {
#if __has_builtin(__builtin_amdgcn_permlane32_swap)
  u2 r = __builtin_amdgcn_permlane32_swap(__builtin_bit_cast(unsigned, v),
                                          __builtin_bit_cast(unsigned, v), false, false);
  return __builtin_bit_cast(float, hi ? r.x : r.y);
#else
  unsigned d = __builtin_bit_cast(unsigned, v), s = d;
  asm volatile("v_permlane32_swap_b32 %0, %1" : "+v"(d), "+v"(s));
  return __builtin_bit_cast(float, hi ? d : s);
#endif
}

__global__ __launch_bounds__(BLK, 1) void lstm2_kernel(
    const float* __restrict__ x,
    const float* __restrict__ Wih0, const float* __restrict__ Whh0,
    const float* __restrict__ bih0, const float* __restrict__ bhh0,
    const float* __restrict__ Wih1, const float* __restrict__ Whh1,
    const float* __restrict__ bih1, const float* __restrict__ bhh1,
    const float* __restrict__ W2,   const float* __restrict__ b2,
    float* __restrict__ out)
{
  __shared__ float obuf[64][16];        // staged output rows, flushed per 64 steps
  __shared__ float xbuf[2][64][32];     // double-buffered 64-step x slices (8KB each):
                                        // keeps global-load latency OFF the recurrence
                                        // chain (R9 theory: x reg-queue PHI forced a
                                        // per-step vmcnt drain ~ HBM latency).

  const int tid = threadIdx.x;
  const int wib = tid >> 6;            // wave in block 0..3
  const int l6  = tid & 63;
  const bool hi = l6 >= 32;            // false: layer-0 lanes, true: layer-1 lanes
  const int j   = l6 & 31;
  const int el  = j >> 3;              // element within wave 0..3
  const int u   = j & 7;               // unit 0..7 (6,7 pads)
  const int uu  = (u < HID) ? u : (HID - 1);
  const int elb = wib * 4 + el;        // element within block 0..15
  const int b   = blockIdx.x * 16 + elb;

  // Per-row constants, rows q = 0..3 (i,f,g,o); gate scale K folded into
  // weights+bias. ABSOLUTE pair order (R7-validated): slot k = {W[2k], W[2k+1]}.
  v2f WA[4][3], WB[4][3];
  float BS[4];
#pragma unroll
  for (int q = 0; q < 4; ++q) {
    const int rq = q * HID + uu;
    const float Kq = (q == 2) ? -2.8853900817779268f : -1.4426950408889634f;
    if (!hi) {
      WA[q][0] = v2f{Kq * Wih0[rq * 2 + 0], Kq * Wih0[rq * 2 + 1]};
      WA[q][1] = v2f{0.f, 0.f};
      WA[q][2] = v2f{0.f, 0.f};
#pragma unroll
      for (int k = 0; k < 3; ++k)
        WB[q][k] = v2f{Kq * Whh0[rq * HID + 2 * k], Kq * Whh0[rq * HID + 2 * k + 1]};
      BS[q] = Kq * (bih0[rq] + bhh0[rq]);
    } else {
#pragma unroll
      for (int k = 0; k < 3; ++k) {
        WA[q][k] = v2f{Kq * Wih1[rq * HID + 2 * k], Kq * Wih1[rq * HID + 2 * k + 1]};
        WB[q][k] = v2f{Kq * Whh1[rq * HID + 2 * k], Kq * Whh1[rq * HID + 2 * k + 1]};
      }
      BS[q] = Kq * (bih1[rq] + bhh1[rq]);
    }
  }
  const v2f w2p0 = v2f{W2[0], W2[1]}, w2p1 = v2f{W2[2], W2[3]}, w2p2 = v2f{W2[4], W2[5]};
  const float bout = b2[0];
  const float KT = 2.8853900817779268f;   // tanh(c) = 1 - 2*rcp(1+exp2(KT*c))

  float h = 0.f, c = 0.f;   // own-layer state: lo = (h0,c0), hi = (h1,c1)

  // absolute-order gather of own-group h (lanes 0..5 real) into 3 pairs
  auto gath = [&](float hv, v2f (&g)[3]) {
    g[0] = v2f{swzf<BC0>(hv), swzf<BC1>(hv)};
    g[1] = v2f{swzf<BC2>(hv), swzf<BC3>(hv)};
    g[2] = v2f{swzf<BC4>(hv), swzf<BC5>(hv)};
  };

  // one fused step: lo computes L0 cell (x, h0-rec), hi computes L1 cell.
  // L1's input gather g1 = permlane32 of the ALREADY-GATHERED g2 pairs
  // (removes the serial second swizzle round-trip from the chain).
  auto step = [&](v2f xc, float& ov) {
    v2f g2[3]; gath(h, g2);                 // own-layer recurrence input
    v2f g1[3];
    g1[0] = v2f{xhalf(g2[0].x, hi), xhalf(g2[0].y, hi)};
    g1[1] = v2f{xhalf(g2[1].x, hi), xhalf(g2[1].y, hi)};
    g1[2] = v2f{xhalf(g2[2].x, hi), xhalf(g2[2].y, hi)};
    v2f v10 = hi ? g1[0] : xc;              // lo: x pair (WA[..][1,2]=0)

    float a[4];
#pragma unroll
    for (int q = 0; q < 4; ++q) {
      v2f accA = __builtin_elementwise_fma(WA[q][0], v10, v2f{BS[q], 0.f});
      accA = __builtin_elementwise_fma(WA[q][1], g1[1], accA);
      accA = __builtin_elementwise_fma(WA[q][2], g1[2], accA);
      v2f accB = WB[q][0] * g2[0];
      accB = __builtin_elementwise_fma(WB[q][1], g2[1], accB);
      accB = __builtin_elementwise_fma(WB[q][2], g2[2], accB);
      v2f acc = accA + accB;
      a[q] = acc.x + acc.y;
    }
    // output row dot from hi's g2 = h1g[t-2]
    v2f ao = __builtin_elementwise_fma(w2p0, g2[0],
             __builtin_elementwise_fma(w2p1, g2[1],
             __builtin_elementwise_fma(w2p2, g2[2], v2f{bout, 0.f})));
    ov = ao.x + ao.y;

    // gates (a pre-scaled): sigma = rcp(1+exp2(a)); g-gate = 2*sigma-1
    float i_ = frcp(1.f + fexp2(a[0]));
    float f_ = frcp(1.f + fexp2(a[1]));
    float g_ = fmaf(2.f, frcp(1.f + fexp2(a[2])), -1.f);
    float o_ = frcp(1.f + fexp2(a[3]));
    c = fmaf(f_, c, i_ * g_);
    float th = fmaf(-2.f, frcp(1.f + fexp2(c * KT)), 1.f);
    h = o_ * th;
  };

  // bulk flush: 64 rows x 16 elements as float4 per thread (full 64B lines)
  auto flush = [&](int rbase) {
    const int r = tid >> 2, jj = (tid & 3) * 4;
    float4 vv = *(const float4*)&obuf[r][jj];
    *(float4*)&out[(size_t)(rbase + r) * BATCH + blockIdx.x * 16 + jj] = vv;
  };

  // ---- prologue: stage x chunks 0 and 1 into LDS ----
  {
    const int row = tid >> 2, jo = (tid & 3) * 8;
    const float* s0 = x + (size_t)row * (BATCH * 2) + blockIdx.x * 32 + jo;
    const float* s1 = s0 + (size_t)64 * (BATCH * 2);
    float4 a0 = *(const float4*)s0, a1 = *(const float4*)(s0 + 4);
    float4 b0 = *(const float4*)s1, b1 = *(const float4*)(s1 + 4);
    *(float4*)&xbuf[0][row][jo]     = a0;
    *(float4*)&xbuf[0][row][jo + 4] = a1;
    *(float4*)&xbuf[1][row][jo]     = b0;
    *(float4*)&xbuf[1][row][jo + 4] = b1;
    __syncthreads();
  }

  v2f xr = *(const v2f*)&xbuf[0][0][elb * 2];

  // t = 0 peel: lo computes h0[0]; hi's result is pre-sequence garbage -> reset
  {
    float ov;
    step(xr, ov);
    if (hi) { h = 0.f; c = 0.f; }
    xr = *(const v2f*)&xbuf[0][1][elb * 2];
  }

  // iteration t: lo -> h0[t] (x[t], h0[t-1]); hi -> h1[t-1] (h0[t-1], h1[t-2]);
  // out row t-2 from hi's recurrence gather. x read 1 step ahead from LDS.
#pragma unroll 1
  for (int t = 1; t < SEQ; ++t) {
    const int tn = (t + 1 < SEQ) ? t + 1 : SEQ - 1;
    v2f xnew = *(const v2f*)&xbuf[(tn >> 6) & 1][tn & 63][elb * 2];

    float ov;
    step(xr, ov);

    if (t >= 2) {
      const int r = t - 2;
      if (hi && u == 0) obuf[r & 63][elb] = ov;
      if ((r & 63) == 63) {            // uniform branch, once per 64 steps
        const int ck = (t >> 6) + 1;   // next x chunk to stage
        const bool doR = (ck * 64 < SEQ);
        const int row = tid >> 2, jo = (tid & 3) * 8;
        float4 a0, a1;
        if (doR) {                     // issue loads BEFORE barrier -> latency
          const float* src = x + ((size_t)(ck * 64) + row) * (BATCH * 2)
                               + blockIdx.x * 32 + jo;   // overlaps the flush
          a0 = *(const float4*)src;
          a1 = *(const float4*)(src + 4);
        }
        __syncthreads();
        flush(r - 63);
        if (doR) {
          *(float4*)&xbuf[ck & 1][row][jo]     = a0;
          *(float4*)&xbuf[ck & 1][row][jo + 4] = a1;
        }
        __syncthreads();
      }
    }
    xr = xnew;
  }

  // epilogue: one more fused step -> h1[S-1] + out row S-2; final gather -> row S-1
  {
    float ov;
    step(xr, ov);
    if (hi && u == 0) obuf[62][elb] = ov;
    v2f g2[3]; gath(h, g2);
    v2f ao = __builtin_elementwise_fma(w2p0, g2[0],
             __builtin_elementwise_fma(w2p1, g2[1],
             __builtin_elementwise_fma(w2p2, g2[2], v2f{bout, 0.f})));
    if (hi && u == 0) obuf[63][elb] = ao.x + ao.y;
    __syncthreads();
    flush(SEQ - 64);
  }
}

extern "C" void kernel_launch(void* const* d_in, const int* in_sizes, int n_in,
                              void* d_out, int out_size, void* d_ws, size_t ws_size,
                              hipStream_t stream) {
  const float* x    = (const float*)d_in[0];
  const float* Wih0 = (const float*)d_in[1];
  const float* Whh0 = (const float*)d_in[2];
  const float* bih0 = (const float*)d_in[3];
  const float* bhh0 = (const float*)d_in[4];
  const float* Wih1 = (const float*)d_in[5];
  const float* Whh1 = (const float*)d_in[6];
  const float* bih1 = (const float*)d_in[7];
  const float* bhh1 = (const float*)d_in[8];
  const float* W2   = (const float*)d_in[9];
  const float* b2   = (const float*)d_in[10];
  float* out = (float*)d_out;

  dim3 grid(BATCH / 16);   // 256 blocks x 4 waves = 1024 waves = 1 wave/SIMD
  dim3 block(BLK);
  hipLaunchKernelGGL(lstm2_kernel, grid, block, 0, stream,
                     x, Wih0, Whh0, bih0, bhh0, Wih1, Whh1, bih1, bhh1, W2, b2, out);
}